// Round 8
// baseline (1125.102 us; speedup 1.0000x reference)
//
#include <hip/hip_runtime.h>
#include <math.h>

#define NGRAPH 512
#define FEATS 288   // (8+1)*32
#define EPS 1e-5f
#define NBAND 4     // src-band count for L2-resident gather (conv sweep)

typedef __attribute__((ext_vector_type(8))) short short8v;
typedef __attribute__((ext_vector_type(8))) unsigned short ushort8v;
typedef __attribute__((ext_vector_type(4))) unsigned short ushort4v;
typedef __attribute__((ext_vector_type(4))) float float4v;

// f32 -> bf16 round-to-nearest-even
__device__ __forceinline__ unsigned short f2bf(float f) {
  unsigned int u = __float_as_uint(f);
  u += 0x7fff + ((u >> 16) & 1);
  return (unsigned short)(u >> 16);
}
__device__ __forceinline__ float bf2f(unsigned short u) {
  return __uint_as_float(((unsigned int)u) << 16);
}

// exact src-band: 3 compares (no div)
__device__ __forceinline__ int srcband(int s, int bandsz) {
  return (s >= bandsz) + (s >= 2 * bandsz) + (s >= 3 * bandsz);
}

// order-preserving float atomic max (works for mixed signs, init -inf)
__device__ __forceinline__ void atomicMaxF(float* addr, float v) {
  if (v >= 0.f) atomicMax((int*)addr, __float_as_int(v));
  else atomicMin((unsigned int*)addr, __float_as_uint(v));
}

// zero/init everything once per call; first 8 blocks also convert weights
// to MFMA fragment order (absorbs the old k_prep launch).
__global__ void k_init(float* __restrict__ pooled, float* __restrict__ counts,
                       float* __restrict__ stats, int* __restrict__ degseg,
                       int* __restrict__ typemask,
                       const float* __restrict__ Wh, const float* __restrict__ Wo,
                       unsigned short* __restrict__ whb, unsigned short* __restrict__ wob,
                       int N4) {
  int i = blockIdx.x * blockDim.x + threadIdx.x;
  if (i < NGRAPH * FEATS) pooled[i] = -INFINITY;
  if (i < NGRAPH) { counts[i] = 0.f; typemask[i] = 0; }
  if (i < NGRAPH * 128) stats[i] = 0.f;       // both buffers
  if (i < N4) degseg[i] = 0;

  if (blockIdx.x < 8) {
    int conv = blockIdx.x;
    const float* wh = Wh + (size_t)conv * 2048;
    const float* wo = Wo + (size_t)conv * 2048;
    unsigned short* oh = whb + (size_t)conv * 2048;
    unsigned short* oo = wob + (size_t)conv * 2048;
    for (int p = threadIdx.x; p < 2048; p += blockDim.x) {
      int rem = p & 511, l = rem >> 3, ii = rem & 7;
      int nt = p >> 9;
      int k = (l >> 4) * 8 + ii;
      int n = nt * 16 + (l & 15);
      oh[p] = f2bf(wh[k * 64 + n]);          // Wh is [32][64]
      int blk = p >> 9, nt2 = blk >> 1, ks = blk & 1;
      int k2 = ks * 32 + (l >> 4) * 8 + ii;
      int n2 = nt2 * 16 + (l & 15);
      oo[p] = f2bf(wo[k2 * 32 + n2]);        // Wo is [64][32]
    }
  }
}

// 8 threads/node: thread q writes channels 4q..4q+3 of hbf (bf16 only).
// Graph-pool of conv-0 features is deferred to k_pool0 via a 6-bit type mask.
__global__ __launch_bounds__(256) void k_embed(
    const int* __restrict__ x, const int* __restrict__ batch,
    const float* __restrict__ emb, unsigned short* __restrict__ hbf,
    int* __restrict__ typemask, float* __restrict__ counts, int N) {
  long t = (long)blockIdx.x * blockDim.x + threadIdx.x;
  int n = (int)(t >> 3), q = (int)(t & 7);
  int lane = threadIdx.x & 63;
  bool valid = (n < N);
  int g = 0, tt = 0;
  if (valid) {
    g = batch[n];
    tt = x[n];
    float4 e = *((const float4*)(emb + (size_t)tt * 32 + q * 4));
    ushort4v hb;
    hb[0] = f2bf(e.x); hb[1] = f2bf(e.y); hb[2] = f2bf(e.z); hb[3] = f2bf(e.w);
    *((ushort4v*)(hbf + (size_t)n * 32 + q * 4)) = hb;
  }
  int g0 = __shfl(g, 0);
  bool uniform = __all(valid) && __all(g == g0);
  int m = valid ? (1 << tt) : 0;
  if (uniform) {
    #pragma unroll
    for (int d = 1; d < 64; d <<= 1) m |= __shfl_xor(m, d);
    if (lane == 0) {
      atomicOr(&typemask[g0], m);
      atomicAdd(&counts[g0], 8.f);   // 64 lanes = 8 nodes
    }
  } else if (valid && q == 0) {
    atomicOr(&typemask[g], m);
    atomicAdd(&counts[g], 1.f);
  }
}

// pooled[g][0:32] = max over types present in g of emb[t][:]
__global__ void k_pool0(const int* __restrict__ typemask, const float* __restrict__ emb,
                        float* __restrict__ pooled) {
  int i = blockIdx.x * blockDim.x + threadIdx.x;
  if (i >= NGRAPH * 32) return;
  int g = i >> 5, c = i & 31;
  int m = typemask[g];
  float v = -INFINITY;
  #pragma unroll
  for (int t = 0; t < 6; t++)
    if (m & (1 << t)) v = fmaxf(v, emb[t * 32 + c]);
  pooled[(size_t)g * FEATS + c] = v;
}

// ---------------- CSR build, src-band partitioned (once per call) --------
// Segment key = dst*4 + srcband. BANDED hist (r6 lesson: de-banding made
// hist 125us with 100MB atomic-RMW writeback — compact per-pass dirty
// window keeps atomic lines cache-resident; banding helps ATOMICS too).
__global__ void k_hist(const int* __restrict__ dst, const int* __restrict__ src,
                       int* __restrict__ degseg, int E,
                       int bandlo, int bandhi, int bandsz) {
  int e = blockIdx.x * blockDim.x + threadIdx.x;
  if (e >= E) return;
  int d = dst[e];
  if (d < bandlo || d >= bandhi) return;
  int sb = srcband(src[e], bandsz);
  atomicAdd(&degseg[(size_t)d * 4 + sb], 1);
}

__global__ void k_scan_block(const int* __restrict__ deg, int* __restrict__ excl,
                             int* __restrict__ bsum, int N) {
  __shared__ int s[256];
  int i = blockIdx.x * 256 + threadIdx.x;
  int t = threadIdx.x;
  int v = (i < N) ? deg[i] : 0;
  s[t] = v;
  __syncthreads();
  for (int off = 1; off < 256; off <<= 1) {
    int add = (t >= off) ? s[t - off] : 0;
    __syncthreads();
    s[t] += add;
    __syncthreads();
  }
  if (i < N) excl[i] = s[t] - v;
  if (t == 255) bsum[blockIdx.x] = s[255];
}

__global__ void k_scan_bsum(int* __restrict__ bsum, int nb) {
  __shared__ int s[256];
  __shared__ int carry;
  int t = threadIdx.x;
  if (t == 0) carry = 0;
  __syncthreads();
  for (int base = 0; base < nb; base += 256) {
    int i = base + t;
    int v = (i < nb) ? bsum[i] : 0;
    s[t] = v;
    __syncthreads();
    for (int off = 1; off < 256; off <<= 1) {
      int add = (t >= off) ? s[t - off] : 0;
      __syncthreads();
      s[t] += add;
      __syncthreads();
    }
    if (i < nb) bsum[i] = s[t] - v + carry;
    __syncthreads();
    if (t == 0) carry += s[255];
    __syncthreads();
  }
}

__global__ void k_scan_add(int* __restrict__ excl, const int* __restrict__ bsum,
                           int* __restrict__ cursor, int N) {
  int i = blockIdx.x * 256 + threadIdx.x;
  if (i < N) {
    int v = excl[i] + bsum[blockIdx.x];
    excl[i] = v;
    cursor[i] = v;
  }
}

// banded scatter: pass r only handles dst in [bandlo, bandhi) so the dirty
// adj region (~3.2 MB at 4 bands) stays L2-resident until lines fill.
__global__ void k_scatter(const int* __restrict__ src, const int* __restrict__ dst,
                          int* __restrict__ cursor, int* __restrict__ adj, int E,
                          int bandlo, int bandhi, int bandsz) {
  int e = blockIdx.x * blockDim.x + threadIdx.x;
  if (e >= E) return;
  int d = dst[e];
  if (d < bandlo || d >= bandhi) return;
  int s = src[e];
  int sb = srcband(s, bandsz);
  int pos = atomicAdd(&cursor[(size_t)d * 4 + sb], 1);
  adj[pos] = s;
}

// ---------------- fused conv: phase-aligned band sweep + quarter-row gather --
// FULLY CO-RESIDENT GRID: 2048 blocks (8/CU), all started together;
// __launch_bounds__(256,8) caps VGPR at 64. Each wave owns up to T=2 tiles
// (stride = gridDim*4 = 8192). Loop order: BAND OUTER, tile inner — all
// resident waves sweep the same src band simultaneously, so each XCD's L2
// holds only that band's hbf slice (~2.8 MB < 4 MB) and re-touches hit.
// GATHER: within a segment, the 4 grp-lanes of a node each load their OWN
// 16B quarter (ch 8*grp..+8) of every neighbor — no butterfly; accumulate
// straight into persistent keepT[t][8]. adj loads NONTEMPORAL (streamed,
// zero reuse — don't evict the hbf band slice). Segment tables hoisted.
// A-frag (16x16x32): lane holds A[row=col][k=grp*8+i]
// C/D: lane reg r = D[row=grp*4+r][col]   (m89)
// z2 stored as bf16. Prologue zeroes the *other* stats buffer.
__global__ __launch_bounds__(256, 8) void k_conv(
    const unsigned short* __restrict__ hbf,
    const int* __restrict__ adj, const int* __restrict__ rowseg,
    const int* __restrict__ degseg,
    const unsigned short* __restrict__ whb, const float* __restrict__ bh,
    const unsigned short* __restrict__ wob, const float* __restrict__ bo,
    const int* __restrict__ batch, unsigned short* __restrict__ z2,
    float* __restrict__ stats, float* __restrict__ statsOther, int N) {
  __shared__ unsigned short sWhB[4 * 64 * 8];     // [nt][lane][i]
  __shared__ unsigned short sWoB[2 * 2 * 64 * 8]; // [nt2*2+ks][lane][i]
  __shared__ unsigned short st[4][16][72];        // per-wave t buf, +8 pad

  {
    int zi = blockIdx.x * 256 + threadIdx.x;
    if (zi < NGRAPH * 64) statsOther[zi] = 0.f;
    int p = threadIdx.x * 8;
    *((ushort8v*)&sWhB[p]) = *((const ushort8v*)&whb[p]);
    *((ushort8v*)&sWoB[p]) = *((const ushort8v*)&wob[p]);
  }
  __syncthreads();

  int wid = threadIdx.x >> 6;
  int lane = threadIdx.x & 63;
  int col = lane & 15;
  int grp = lane >> 4;
  int gwave = blockIdx.x * 4 + wid;        // 0..8191
  int wstride = gridDim.x * 4;             // 8192
  int ntiles = (N + 15) >> 4;

  // quarter base: this lane only ever touches ch 8*grp..8*grp+7 of any row
  const unsigned short* __restrict__ qb = hbf + grp * 8;

  // hoist per-tile segment tables (one int4 pair per tile)
  int sA[2][4], dA[2][4];
  #pragma unroll
  for (int t = 0; t < 2; t++) {
    #pragma unroll
    for (int b = 0; b < 4; b++) { sA[t][b] = 0; dA[t][b] = 0; }
    int tile = gwave + t * wstride;
    if (tile < ntiles) {
      int node = tile * 16 + col;
      if (node < N) {
        int4 s4 = *((const int4*)(rowseg + (size_t)node * 4));
        int4 d4 = *((const int4*)(degseg + (size_t)node * 4));
        sA[t][0] = s4.x; sA[t][1] = s4.y; sA[t][2] = s4.z; sA[t][3] = s4.w;
        dA[t][0] = d4.x; dA[t][1] = d4.y; dA[t][2] = d4.z; dA[t][3] = d4.w;
      }
    }
  }

  // persistent per-tile accumulators (lane grp holds ch 8*grp..8*grp+7)
  float keepT[2][8];
  #pragma unroll
  for (int t = 0; t < 2; t++)
    #pragma unroll
    for (int i = 0; i < 8; i++) keepT[t][i] = 0.f;

  // band-major gather sweep
  #pragma unroll
  for (int b = 0; b < 4; b++) {
    #pragma unroll
    for (int t = 0; t < 2; t++) {
      int tile = gwave + t * wstride;
      if (tile >= ntiles) continue;        // wave-uniform branch
      int s0 = sA[t][b], dg = dA[t][b];
      int k = 0;
      for (; k + 4 <= dg; k += 4) {
        int nA = __builtin_nontemporal_load(adj + s0 + k + 0);
        int nB = __builtin_nontemporal_load(adj + s0 + k + 1);
        int nC = __builtin_nontemporal_load(adj + s0 + k + 2);
        int nD = __builtin_nontemporal_load(adj + s0 + k + 3);
        ushort8v a = *((const ushort8v*)(qb + (size_t)nA * 32));
        ushort8v bv = *((const ushort8v*)(qb + (size_t)nB * 32));
        ushort8v c = *((const ushort8v*)(qb + (size_t)nC * 32));
        ushort8v d = *((const ushort8v*)(qb + (size_t)nD * 32));
        #pragma unroll
        for (int i = 0; i < 8; i++) {
          keepT[t][i] += bf2f(a[i]);
          keepT[t][i] += bf2f(bv[i]);
          keepT[t][i] += bf2f(c[i]);
          keepT[t][i] += bf2f(d[i]);
        }
      }
      if (k + 2 <= dg) {
        int nA = __builtin_nontemporal_load(adj + s0 + k + 0);
        int nB = __builtin_nontemporal_load(adj + s0 + k + 1);
        ushort8v a = *((const ushort8v*)(qb + (size_t)nA * 32));
        ushort8v bv = *((const ushort8v*)(qb + (size_t)nB * 32));
        #pragma unroll
        for (int i = 0; i < 8; i++) {
          keepT[t][i] += bf2f(a[i]);
          keepT[t][i] += bf2f(bv[i]);
        }
        k += 2;
      }
      if (k < dg) {
        int nA = __builtin_nontemporal_load(adj + s0 + k);
        ushort8v a = *((const ushort8v*)(qb + (size_t)nA * 32));
        #pragma unroll
        for (int i = 0; i < 8; i++) keepT[t][i] += bf2f(a[i]);
      }
    }
  }

  // epilogue per tile: z -> MLP -> z2, stats
  #pragma unroll
  for (int t = 0; t < 2; t++) {
    int tile = gwave + t * wstride;
    if (tile >= ntiles) continue;
    int base = tile * 16;
    int node = base + col;

    float zf[8];
    if (node < N) {
      ushort8v own = *((const ushort8v*)(hbf + (size_t)node * 32 + grp * 8));
      #pragma unroll
      for (int i = 0; i < 8; i++) zf[i] = bf2f(own[i]) + keepT[t][i];
    } else {
      #pragma unroll
      for (int i = 0; i < 8; i++) zf[i] = 0.f;
    }
    short8v afrag;
    #pragma unroll
    for (int i = 0; i < 8; i++) afrag[i] = (short)f2bf(zf[i]);

    // layer 1: t1 = relu(z @ Wh + bh) -> bf16 in per-wave LDS
    #pragma unroll
    for (int nt = 0; nt < 4; nt++) {
      float b = bh[nt * 16 + col];
      float4v acc1 = {b, b, b, b};
      short8v bfrag = *((const short8v*)&sWhB[(nt * 64 + lane) * 8]);
      acc1 = __builtin_amdgcn_mfma_f32_16x16x32_bf16(afrag, bfrag, acc1, 0, 0, 0);
      #pragma unroll
      for (int r = 0; r < 4; r++) {
        st[wid][grp * 4 + r][nt * 16 + col] = f2bf(fmaxf(acc1[r], 0.f));
      }
    }
    // same-wave LDS RAW/WAR: DS ops are in-order per wave; compiler inserts lgkmcnt.

    // layer 2: o = t1 @ Wo + bo
    short8v a2[2];
    #pragma unroll
    for (int ks = 0; ks < 2; ks++)
      a2[ks] = *((const short8v*)&st[wid][col][ks * 32 + grp * 8]);

    float4v acc2[2];
    #pragma unroll
    for (int nt2 = 0; nt2 < 2; nt2++) {
      float b = bo[nt2 * 16 + col];
      acc2[nt2] = (float4v){b, b, b, b};
      #pragma unroll
      for (int ks = 0; ks < 2; ks++) {
        short8v bfrag = *((const short8v*)&sWoB[((nt2 * 2 + ks) * 64 + lane) * 8]);
        acc2[nt2] = __builtin_amdgcn_mfma_f32_16x16x32_bf16(a2[ks], bfrag, acc2[nt2], 0, 0, 0);
      }
    }

    // store z2 (bf16, nt streaming store)
    #pragma unroll
    for (int nt2 = 0; nt2 < 2; nt2++) {
      #pragma unroll
      for (int r = 0; r < 4; r++) {
        int nd = base + grp * 4 + r;
        if (nd < N)
          __builtin_nontemporal_store(f2bf(acc2[nt2][r]), z2 + (size_t)nd * 32 + nt2 * 16 + col);
      }
    }

    // per-graph stats
    int g0 = batch[base];
    int gLast = batch[min(base + 15, N - 1)];
    if ((base + 16 <= N) && g0 == gLast) {
      #pragma unroll
      for (int nt2 = 0; nt2 < 2; nt2++) {
        float s = acc2[nt2][0] + acc2[nt2][1] + acc2[nt2][2] + acc2[nt2][3];
        float ss = acc2[nt2][0] * acc2[nt2][0] + acc2[nt2][1] * acc2[nt2][1]
                 + acc2[nt2][2] * acc2[nt2][2] + acc2[nt2][3] * acc2[nt2][3];
        s += __shfl_xor(s, 16); s += __shfl_xor(s, 32);
        ss += __shfl_xor(ss, 16); ss += __shfl_xor(ss, 32);
        if (grp == 0) {
          atomicAdd(&stats[(size_t)g0 * 64 + nt2 * 16 + col], s);
          atomicAdd(&stats[(size_t)g0 * 64 + 32 + nt2 * 16 + col], ss);
        }
      }
    } else {
      #pragma unroll
      for (int nt2 = 0; nt2 < 2; nt2++) {
        #pragma unroll
        for (int r = 0; r < 4; r++) {
          int nd = base + grp * 4 + r;
          if (nd < N) {
            int g = batch[nd];
            float v = acc2[nt2][r];
            atomicAdd(&stats[(size_t)g * 64 + nt2 * 16 + col], v);
            atomicAdd(&stats[(size_t)g * 64 + 32 + nt2 * 16 + col], v * v);
          }
        }
      }
    }
  }
}

// ---------------- conv 0 specialization ----------------
// At conv 0, h = emb[x] has only 6 distinct rows, so the neighbor gather
// collapses to type-counting. Row is contiguous across band segments:
// start = seg0 start, deg = sum of seg degs.
__global__ __launch_bounds__(256, 4) void k_conv0(
    const unsigned short* __restrict__ hbf,
    const int* __restrict__ adj, const int* __restrict__ rowseg,
    const int* __restrict__ degseg,
    const int* __restrict__ x, const float* __restrict__ emb,
    const unsigned short* __restrict__ whb, const float* __restrict__ bh,
    const unsigned short* __restrict__ wob, const float* __restrict__ bo,
    const int* __restrict__ batch, unsigned short* __restrict__ z2,
    float* __restrict__ stats, float* __restrict__ statsOther, int N) {
  __shared__ unsigned short sWhB[4 * 64 * 8];
  __shared__ unsigned short sWoB[2 * 2 * 64 * 8];
  __shared__ unsigned short st[4][16][72];
  __shared__ float sEmb[6][32];

  {
    int zi = blockIdx.x * 256 + threadIdx.x;
    if (zi < NGRAPH * 64) statsOther[zi] = 0.f;
    int p = threadIdx.x * 8;
    *((ushort8v*)&sWhB[p]) = *((const ushort8v*)&whb[p]);
    *((ushort8v*)&sWoB[p]) = *((const ushort8v*)&wob[p]);
    if (threadIdx.x < 192) ((float*)sEmb)[threadIdx.x] = emb[threadIdx.x];
  }
  __syncthreads();

  int wid = threadIdx.x >> 6;
  int lane = threadIdx.x & 63;
  int tile = blockIdx.x * 4 + wid;
  int base = tile * 16;
  if (base >= N) return;
  int col = lane & 15;
  int grp = lane >> 4;
  int node = base + col;

  int s0 = 0, dg = 0;
  if (node < N) {
    int4 s4 = *((const int4*)(rowseg + (size_t)node * 4));
    int4 d4 = *((const int4*)(degseg + (size_t)node * 4));
    s0 = s4.x;
    dg = d4.x + d4.y + d4.z + d4.w;
  }

  // count neighbor types over this lane's subset (j == grp mod 4)
  float c0 = 0.f, c1 = 0.f, c2 = 0.f, c3 = 0.f, c4 = 0.f, c5 = 0.f;
  int j = grp;
  for (; j + 4 < dg; j += 8) {
    int sAi = __builtin_nontemporal_load(adj + s0 + j);
    int sBi = __builtin_nontemporal_load(adj + s0 + j + 4);
    int tA = x[sAi];
    int tB = x[sBi];
    c0 += (tA == 0) ? 1.f : 0.f; c1 += (tA == 1) ? 1.f : 0.f;
    c2 += (tA == 2) ? 1.f : 0.f; c3 += (tA == 3) ? 1.f : 0.f;
    c4 += (tA == 4) ? 1.f : 0.f; c5 += (tA == 5) ? 1.f : 0.f;
    c0 += (tB == 0) ? 1.f : 0.f; c1 += (tB == 1) ? 1.f : 0.f;
    c2 += (tB == 2) ? 1.f : 0.f; c3 += (tB == 3) ? 1.f : 0.f;
    c4 += (tB == 4) ? 1.f : 0.f; c5 += (tB == 5) ? 1.f : 0.f;
  }
  if (j < dg) {
    int sAi = __builtin_nontemporal_load(adj + s0 + j);
    int tA = x[sAi];
    c0 += (tA == 0) ? 1.f : 0.f; c1 += (tA == 1) ? 1.f : 0.f;
    c2 += (tA == 2) ? 1.f : 0.f; c3 += (tA == 3) ? 1.f : 0.f;
    c4 += (tA == 4) ? 1.f : 0.f; c5 += (tA == 5) ? 1.f : 0.f;
  }

  // all-reduce counts across the 4 grp-lanes of each node (col preserved)
  c0 += __shfl_xor(c0, 16); c0 += __shfl_xor(c0, 32);
  c1 += __shfl_xor(c1, 16); c1 += __shfl_xor(c1, 32);
  c2 += __shfl_xor(c2, 16); c2 += __shfl_xor(c2, 32);
  c3 += __shfl_xor(c3, 16); c3 += __shfl_xor(c3, 32);
  c4 += __shfl_xor(c4, 16); c4 += __shfl_xor(c4, 32);
  c5 += __shfl_xor(c5, 16); c5 += __shfl_xor(c5, 32);

  // z = h_own + sum_t c_t * emb[t]   (lane grp holds ch 8*grp..8*grp+7)
  float zf[8];
  if (node < N) {
    ushort8v own = *((const ushort8v*)(hbf + (size_t)node * 32 + grp * 8));
    #pragma unroll
    for (int i = 0; i < 8; i++) {
      int ch = grp * 8 + i;
      float v = bf2f(own[i]);
      v = fmaf(c0, sEmb[0][ch], v);
      v = fmaf(c1, sEmb[1][ch], v);
      v = fmaf(c2, sEmb[2][ch], v);
      v = fmaf(c3, sEmb[3][ch], v);
      v = fmaf(c4, sEmb[4][ch], v);
      v = fmaf(c5, sEmb[5][ch], v);
      zf[i] = v;
    }
  } else {
    #pragma unroll
    for (int i = 0; i < 8; i++) zf[i] = 0.f;
  }
  short8v afrag;
  #pragma unroll
  for (int i = 0; i < 8; i++) afrag[i] = (short)f2bf(zf[i]);

  // layer 1: t = relu(z @ Wh + bh) -> bf16 t in per-wave LDS
  #pragma unroll
  for (int nt = 0; nt < 4; nt++) {
    float b = bh[nt * 16 + col];
    float4v acc1 = {b, b, b, b};
    short8v bfrag = *((const short8v*)&sWhB[(nt * 64 + lane) * 8]);
    acc1 = __builtin_amdgcn_mfma_f32_16x16x32_bf16(afrag, bfrag, acc1, 0, 0, 0);
    #pragma unroll
    for (int r = 0; r < 4; r++) {
      st[wid][grp * 4 + r][nt * 16 + col] = f2bf(fmaxf(acc1[r], 0.f));
    }
  }

  // layer 2: o = t @ Wo + bo
  short8v a2[2];
  #pragma unroll
  for (int ks = 0; ks < 2; ks++)
    a2[ks] = *((const short8v*)&st[wid][col][ks * 32 + grp * 8]);

  float4v acc2[2];
  #pragma unroll
  for (int nt2 = 0; nt2 < 2; nt2++) {
    float b = bo[nt2 * 16 + col];
    acc2[nt2] = (float4v){b, b, b, b};
    #pragma unroll
    for (int ks = 0; ks < 2; ks++) {
      short8v bfrag = *((const short8v*)&sWoB[((nt2 * 2 + ks) * 64 + lane) * 8]);
      acc2[nt2] = __builtin_amdgcn_mfma_f32_16x16x32_bf16(a2[ks], bfrag, acc2[nt2], 0, 0, 0);
    }
  }

  // store z2 (bf16, nt streaming store)
  #pragma unroll
  for (int nt2 = 0; nt2 < 2; nt2++) {
    #pragma unroll
    for (int r = 0; r < 4; r++) {
      int nd = base + grp * 4 + r;
      if (nd < N)
        __builtin_nontemporal_store(f2bf(acc2[nt2][r]), z2 + (size_t)nd * 32 + nt2 * 16 + col);
    }
  }

  // per-graph stats
  int g0 = batch[base];
  int gLast = batch[min(base + 15, N - 1)];
  if ((base + 16 <= N) && g0 == gLast) {
    #pragma unroll
    for (int nt2 = 0; nt2 < 2; nt2++) {
      float s = acc2[nt2][0] + acc2[nt2][1] + acc2[nt2][2] + acc2[nt2][3];
      float ss = acc2[nt2][0] * acc2[nt2][0] + acc2[nt2][1] * acc2[nt2][1]
               + acc2[nt2][2] * acc2[nt2][2] + acc2[nt2][3] * acc2[nt2][3];
      s += __shfl_xor(s, 16); s += __shfl_xor(s, 32);
      ss += __shfl_xor(ss, 16); ss += __shfl_xor(ss, 32);
      if (grp == 0) {
        atomicAdd(&stats[(size_t)g0 * 64 + nt2 * 16 + col], s);
        atomicAdd(&stats[(size_t)g0 * 64 + 32 + nt2 * 16 + col], ss);
      }
    }
  } else {
    #pragma unroll
    for (int nt2 = 0; nt2 < 2; nt2++) {
      #pragma unroll
      for (int r = 0; r < 4; r++) {
        int nd = base + grp * 4 + r;
        if (nd < N) {
          int g = batch[nd];
          float v = acc2[nt2][r];
          atomicAdd(&stats[(size_t)g * 64 + nt2 * 16 + col], v);
          atomicAdd(&stats[(size_t)g * 64 + 32 + nt2 * 16 + col], v * v);
        }
      }
    }
  }
}

// h = relu(h + (z2-mean)*inv), hbf kept bf16. 4 threads/node, 8 ch each
// (ushort8 16B loads; half the blocks and half the redundant stats reads
// of the old 8-thr/node version). Wave covers 16 consecutive nodes.
__global__ __launch_bounds__(256) void k_norm(
    unsigned short* __restrict__ hbf, const unsigned short* __restrict__ z2,
    const float* __restrict__ stats, const float* __restrict__ counts,
    const int* __restrict__ batch, float* __restrict__ pooled, int conv, int N) {
  long t = (long)blockIdx.x * blockDim.x + threadIdx.x;
  int n = (int)(t >> 2), q = (int)(t & 3);
  int lane = threadIdx.x & 63;
  bool valid = (n < N);

  int g = 0;
  float rr[8];
  #pragma unroll
  for (int i = 0; i < 8; i++) rr[i] = -INFINITY;

  if (valid) {
    g = batch[n];
    float cnt = counts[g];
    float rc = (cnt > 0.f) ? (1.f / cnt) : 0.f;
    const float* sb = stats + (size_t)g * 64 + q * 8;
    float4 s0 = *((const float4*)(sb));
    float4 s1 = *((const float4*)(sb + 4));
    float4 q0 = *((const float4*)(sb + 32));
    float4 q1 = *((const float4*)(sb + 36));
    float sa[8] = {s0.x, s0.y, s0.z, s0.w, s1.x, s1.y, s1.z, s1.w};
    float qa[8] = {q0.x, q0.y, q0.z, q0.w, q1.x, q1.y, q1.z, q1.w};
    ushort8v hb = *((const ushort8v*)(hbf + (size_t)n * 32 + q * 8));
    ushort8v zv = *((const ushort8v*)(z2 + (size_t)n * 32 + q * 8));
    ushort8v hnew;
    #pragma unroll
    for (int i = 0; i < 8; i++) {
      float m = sa[i] * rc;
      float inv = rsqrtf(fmaxf(qa[i] * rc - m * m, 0.f) + EPS);
      float r = fmaxf(bf2f(hb[i]) + (bf2f(zv[i]) - m) * inv, 0.f);
      rr[i] = r;
      hnew[i] = f2bf(r);
    }
    *((ushort8v*)(hbf + (size_t)n * 32 + q * 8)) = hnew;
  }

  // pool: max over the wave's 16 nodes per channel (lane = node*4 + q)
  int g0 = __shfl(g, 0);
  bool uniform = __all(valid) && __all(g == g0);
  if (uniform) {
    #pragma unroll
    for (int i = 0; i < 8; i++) {
      float m = rr[i];
      m = fmaxf(m, __shfl_xor(m, 4));
      m = fmaxf(m, __shfl_xor(m, 8));
      m = fmaxf(m, __shfl_xor(m, 16));
      m = fmaxf(m, __shfl_xor(m, 32));
      rr[i] = m;
    }
    if (lane < 4) {
      float* poolrow = pooled + (size_t)g0 * FEATS + (conv + 1) * 32 + lane * 8;
      #pragma unroll
      for (int i = 0; i < 8; i++) atomicMaxF(poolrow + i, rr[i]);
    }
  } else if (valid) {
    float* poolrow = pooled + (size_t)g * FEATS + (conv + 1) * 32 + q * 8;
    #pragma unroll
    for (int i = 0; i < 8; i++) atomicMaxF(poolrow + i, rr[i]);
  }
}

// hid = relu(pooled @ W_hid + b_hid); out = hid @ W_out + b_out
__global__ __launch_bounds__(64) void k_head(
    const float* __restrict__ pooled, const float* __restrict__ W_hid,
    const float* __restrict__ b_hid, const float* __restrict__ W_out,
    const float* __restrict__ b_out, float* __restrict__ out) {
  __shared__ float sp[FEATS];
  __shared__ float sh[64];
  int g = blockIdx.x;
  for (int i = threadIdx.x; i < FEATS; i += 64) sp[i] = pooled[(size_t)g * FEATS + i];
  __syncthreads();
  int j = threadIdx.x;
  float acc = b_hid[j];
  for (int k = 0; k < FEATS; k++) acc = fmaf(sp[k], W_hid[k * 64 + j], acc);
  sh[j] = fmaxf(acc, 0.f);
  __syncthreads();
  if (j < 32) {
    float o = b_out[j];
    #pragma unroll
    for (int k = 0; k < 64; k++) o = fmaf(sh[k], W_out[k * 32 + j], o);
    out[(size_t)g * 32 + j] = o;
  }
}

extern "C" void kernel_launch(void* const* d_in, const int* in_sizes, int n_in,
                              void* d_out, int out_size, void* d_ws, size_t ws_size,
                              hipStream_t stream) {
  const int* x      = (const int*)d_in[0];
  const int* edge   = (const int*)d_in[1];
  const int* batch  = (const int*)d_in[2];
  const float* emb  = (const float*)d_in[3];
  const float* Wh   = (const float*)d_in[4];
  const float* bh   = (const float*)d_in[5];
  const float* Wo   = (const float*)d_in[6];
  const float* bo   = (const float*)d_in[7];
  const float* W_hid = (const float*)d_in[8];
  const float* b_hid = (const float*)d_in[9];
  const float* W_out = (const float*)d_in[10];
  const float* b_out = (const float*)d_in[11];
  float* out = (float*)d_out;

  int N = in_sizes[0];
  int E = in_sizes[1] / 2;
  const int* src = edge;
  const int* dst = edge + E;

  int N4 = N * 4;
  int bandsz = (N + NBAND - 1) / NBAND;   // src band size (hbf slice 3.2 MB)

  float* ws = (float*)d_ws;
  size_t off = 0;
  unsigned short* z2 = (unsigned short*)(ws + off); off += (size_t)N * 16; // N*32 bf16
  float* pooled  = ws + off; off += (size_t)NGRAPH * FEATS;
  float* stats   = ws + off; off += (size_t)NGRAPH * 128;   // double buffer
  float* counts  = ws + off; off += NGRAPH;
  unsigned short* hbf = (unsigned short*)(ws + off); off += (size_t)N * 16; // N*32 ushorts
  unsigned short* whb = (unsigned short*)(ws + off); off += 8192;  // 8*2048 ushorts
  unsigned short* wob = (unsigned short*)(ws + off); off += 8192;
  int* iws = (int*)(ws + off);
  size_t ioff = 0;
  int* degseg   = iws + ioff; ioff += N4;   // [dst][srcband]
  int* rowseg   = iws + ioff; ioff += N4;
  int* cursor   = iws + ioff; ioff += N4;
  int* adj      = iws + ioff; ioff += E;
  int* bsum     = iws + ioff; ioff += 4096;
  int* typemask = iws + ioff; ioff += NGRAPH;

  int eb = (E + 255) / 256;
  int nb4 = (N4 + 255) / 256;               // scan over 4N segment counters
  int nb8 = (int)(((size_t)N * 8 + 255) / 256);
  int nbn = (int)(((size_t)N * 4 + 255) / 256);  // k_norm: 4 threads/node
  int tiles = (N + 15) / 16;
  int mb = (tiles + 3) / 4;   // conv0: 4 waves (tiles) per block
  int ib = nb4;               // k_init grid covers max(4N, NGRAPH*FEATS)
  if (ib < (NGRAPH * FEATS + 255) / 256) ib = (NGRAPH * FEATS + 255) / 256;

  k_init<<<ib, 256, 0, stream>>>(pooled, counts, stats, degseg, typemask,
                                 Wh, Wo, whb, wob, N4);
  k_embed<<<nb8, 256, 0, stream>>>(x, batch, emb, hbf, typemask, counts, N);
  k_pool0<<<(NGRAPH * 32 + 255) / 256, 256, 0, stream>>>(typemask, emb, pooled);

  // CSR build: 4-band hist + 4-band scatter (banding helps atomics — r6 lesson)
  int dband = (N + NBAND - 1) / NBAND;
  for (int r = 0; r < NBAND; r++) {
    int lo = r * dband;
    int hi = (r == NBAND - 1) ? N : (r + 1) * dband;
    k_hist<<<eb, 256, 0, stream>>>(dst, src, degseg, E, lo, hi, bandsz);
  }
  k_scan_block<<<nb4, 256, 0, stream>>>(degseg, rowseg, bsum, N4);
  k_scan_bsum<<<1, 256, 0, stream>>>(bsum, nb4);
  k_scan_add<<<nb4, 256, 0, stream>>>(rowseg, bsum, cursor, N4);
  for (int r = 0; r < NBAND; r++) {
    int lo = r * dband;
    int hi = (r == NBAND - 1) ? N : (r + 1) * dband;
    k_scatter<<<eb, 256, 0, stream>>>(src, dst, cursor, adj, E, lo, hi, bandsz);
  }

  // fully co-resident conv grid: 8 blocks/CU x 256 CUs
  const int GCONV = 2048;

  for (int i = 0; i < 8; i++) {
    float* sCur = stats + (size_t)(i & 1) * NGRAPH * 64;
    float* sOth = stats + (size_t)((i + 1) & 1) * NGRAPH * 64;
    if (i == 0) {
      k_conv0<<<mb, 256, 0, stream>>>(hbf, adj, rowseg, degseg, x, emb,
                                      whb, bh, wob, bo,
                                      batch, z2, sCur, sOth, N);
    } else {
      k_conv<<<GCONV, 256, 0, stream>>>(hbf, adj, rowseg, degseg,
                                        whb + (size_t)i * 2048, bh + (size_t)i * 64,
                                        wob + (size_t)i * 2048, bo + (size_t)i * 32,
                                        batch, z2, sCur, sOth, N);
    }
    k_norm<<<nbn, 256, 0, stream>>>(hbf, z2, sCur, counts, batch, pooled, i, N);
  }
  k_head<<<NGRAPH, 64, 0, stream>>>(pooled, W_hid, b_hid, W_out, b_out, out);
}

// Round 9
// 1022.884 us; speedup vs baseline: 1.0999x; 1.0999x over previous
//
#include <hip/hip_runtime.h>
#include <math.h>

#define NGRAPH 512
#define FEATS 288   // (8+1)*32
#define EPS 1e-5f
#define NBAND 4     // src-band count for L2-resident gather (conv sweep)

typedef __attribute__((ext_vector_type(8))) short short8v;
typedef __attribute__((ext_vector_type(8))) unsigned short ushort8v;
typedef __attribute__((ext_vector_type(4))) unsigned short ushort4v;
typedef __attribute__((ext_vector_type(4))) float float4v;

// f32 -> bf16 round-to-nearest-even
__device__ __forceinline__ unsigned short f2bf(float f) {
  unsigned int u = __float_as_uint(f);
  u += 0x7fff + ((u >> 16) & 1);
  return (unsigned short)(u >> 16);
}
__device__ __forceinline__ float bf2f(unsigned short u) {
  return __uint_as_float(((unsigned int)u) << 16);
}

// exact src-band: 3 compares (no div)
__device__ __forceinline__ int srcband(int s, int bandsz) {
  return (s >= bandsz) + (s >= 2 * bandsz) + (s >= 3 * bandsz);
}

// order-preserving float atomic max (works for mixed signs, init -inf)
__device__ __forceinline__ void atomicMaxF(float* addr, float v) {
  if (v >= 0.f) atomicMax((int*)addr, __float_as_int(v));
  else atomicMin((unsigned int*)addr, __float_as_uint(v));
}

// zero/init everything once per call; first 8 blocks also convert weights
// to MFMA fragment order (absorbs the old k_prep launch).
__global__ void k_init(float* __restrict__ pooled, float* __restrict__ counts,
                       float* __restrict__ stats, int* __restrict__ degseg,
                       int* __restrict__ typemask,
                       const float* __restrict__ Wh, const float* __restrict__ Wo,
                       unsigned short* __restrict__ whb, unsigned short* __restrict__ wob,
                       int N4) {
  int i = blockIdx.x * blockDim.x + threadIdx.x;
  if (i < NGRAPH * FEATS) pooled[i] = -INFINITY;
  if (i < NGRAPH) { counts[i] = 0.f; typemask[i] = 0; }
  if (i < NGRAPH * 128) stats[i] = 0.f;       // both buffers
  if (i < N4) degseg[i] = 0;

  if (blockIdx.x < 8) {
    int conv = blockIdx.x;
    const float* wh = Wh + (size_t)conv * 2048;
    const float* wo = Wo + (size_t)conv * 2048;
    unsigned short* oh = whb + (size_t)conv * 2048;
    unsigned short* oo = wob + (size_t)conv * 2048;
    for (int p = threadIdx.x; p < 2048; p += blockDim.x) {
      int rem = p & 511, l = rem >> 3, ii = rem & 7;
      int nt = p >> 9;
      int k = (l >> 4) * 8 + ii;
      int n = nt * 16 + (l & 15);
      oh[p] = f2bf(wh[k * 64 + n]);          // Wh is [32][64]
      int blk = p >> 9, nt2 = blk >> 1, ks = blk & 1;
      int k2 = ks * 32 + (l >> 4) * 8 + ii;
      int n2 = nt2 * 16 + (l & 15);
      oo[p] = f2bf(wo[k2 * 32 + n2]);        // Wo is [64][32]
    }
  }
}

// 8 threads/node: thread q writes channels 4q..4q+3 of hbf (bf16 only).
// Graph-pool of conv-0 features is deferred to k_pool0 via a 6-bit type mask.
__global__ __launch_bounds__(256) void k_embed(
    const int* __restrict__ x, const int* __restrict__ batch,
    const float* __restrict__ emb, unsigned short* __restrict__ hbf,
    int* __restrict__ typemask, float* __restrict__ counts, int N) {
  long t = (long)blockIdx.x * blockDim.x + threadIdx.x;
  int n = (int)(t >> 3), q = (int)(t & 7);
  int lane = threadIdx.x & 63;
  bool valid = (n < N);
  int g = 0, tt = 0;
  if (valid) {
    g = batch[n];
    tt = x[n];
    float4 e = *((const float4*)(emb + (size_t)tt * 32 + q * 4));
    ushort4v hb;
    hb[0] = f2bf(e.x); hb[1] = f2bf(e.y); hb[2] = f2bf(e.z); hb[3] = f2bf(e.w);
    *((ushort4v*)(hbf + (size_t)n * 32 + q * 4)) = hb;
  }
  int g0 = __shfl(g, 0);
  bool uniform = __all(valid) && __all(g == g0);
  int m = valid ? (1 << tt) : 0;
  if (uniform) {
    #pragma unroll
    for (int d = 1; d < 64; d <<= 1) m |= __shfl_xor(m, d);
    if (lane == 0) {
      atomicOr(&typemask[g0], m);
      atomicAdd(&counts[g0], 8.f);   // 64 lanes = 8 nodes
    }
  } else if (valid && q == 0) {
    atomicOr(&typemask[g], m);
    atomicAdd(&counts[g], 1.f);
  }
}

// pooled[g][0:32] = max over types present in g of emb[t][:]
__global__ void k_pool0(const int* __restrict__ typemask, const float* __restrict__ emb,
                        float* __restrict__ pooled) {
  int i = blockIdx.x * blockDim.x + threadIdx.x;
  if (i >= NGRAPH * 32) return;
  int g = i >> 5, c = i & 31;
  int m = typemask[g];
  float v = -INFINITY;
  #pragma unroll
  for (int t = 0; t < 6; t++)
    if (m & (1 << t)) v = fmaxf(v, emb[t * 32 + c]);
  pooled[(size_t)g * FEATS + c] = v;
}

// ---------------- CSR build, src-band partitioned (once per call) --------
// Segment key = dst*4 + srcband. Banded processing kept (r6 lesson: the
// compact per-band dirty window keeps atomic lines cache-resident), but the
// 4 band passes are now ONE launch: band = blockIdx.x / eb. Blocks dispatch
// in ascending ID order and are short/uniform, so resident blocks span <=2
// bands at any instant — temporal banding preserved, 3 launch gaps saved.
__global__ void k_hist(const int* __restrict__ dst, const int* __restrict__ src,
                       int* __restrict__ degseg, int E, int eb,
                       int dband, int bandsz, int N) {
  int band = blockIdx.x / eb;
  int e = (blockIdx.x - band * eb) * blockDim.x + threadIdx.x;
  if (e >= E) return;
  int bandlo = band * dband;
  int bandhi = min(bandlo + dband, N);
  int d = dst[e];
  if (d < bandlo || d >= bandhi) return;
  int sb = srcband(src[e], bandsz);
  atomicAdd(&degseg[(size_t)d * 4 + sb], 1);
}

__global__ void k_scan_block(const int* __restrict__ deg, int* __restrict__ excl,
                             int* __restrict__ bsum, int N) {
  __shared__ int s[256];
  int i = blockIdx.x * 256 + threadIdx.x;
  int t = threadIdx.x;
  int v = (i < N) ? deg[i] : 0;
  s[t] = v;
  __syncthreads();
  for (int off = 1; off < 256; off <<= 1) {
    int add = (t >= off) ? s[t - off] : 0;
    __syncthreads();
    s[t] += add;
    __syncthreads();
  }
  if (i < N) excl[i] = s[t] - v;
  if (t == 255) bsum[blockIdx.x] = s[255];
}

__global__ void k_scan_bsum(int* __restrict__ bsum, int nb) {
  __shared__ int s[256];
  __shared__ int carry;
  int t = threadIdx.x;
  if (t == 0) carry = 0;
  __syncthreads();
  for (int base = 0; base < nb; base += 256) {
    int i = base + t;
    int v = (i < nb) ? bsum[i] : 0;
    s[t] = v;
    __syncthreads();
    for (int off = 1; off < 256; off <<= 1) {
      int add = (t >= off) ? s[t - off] : 0;
      __syncthreads();
      s[t] += add;
      __syncthreads();
    }
    if (i < nb) bsum[i] = s[t] - v + carry;
    __syncthreads();
    if (t == 0) carry += s[255];
    __syncthreads();
  }
}

__global__ void k_scan_add(int* __restrict__ excl, const int* __restrict__ bsum,
                           int* __restrict__ cursor, int N) {
  int i = blockIdx.x * 256 + threadIdx.x;
  if (i < N) {
    int v = excl[i] + bsum[blockIdx.x];
    excl[i] = v;
    cursor[i] = v;
  }
}

// banded scatter, single launch (band = blockIdx.x / eb, as k_hist).
__global__ void k_scatter(const int* __restrict__ src, const int* __restrict__ dst,
                          int* __restrict__ cursor, int* __restrict__ adj, int E,
                          int eb, int dband, int bandsz, int N) {
  int band = blockIdx.x / eb;
  int e = (blockIdx.x - band * eb) * blockDim.x + threadIdx.x;
  if (e >= E) return;
  int bandlo = band * dband;
  int bandhi = min(bandlo + dband, N);
  int d = dst[e];
  if (d < bandlo || d >= bandhi) return;
  int s = src[e];
  int sb = srcband(s, bandsz);
  int pos = atomicAdd(&cursor[(size_t)d * 4 + sb], 1);
  adj[pos] = s;
}

// ---------------- fused conv: phase-aligned band sweep + quarter-row gather --
// r5 config VERBATIM (measured 59us, FETCH 138MB): FULLY CO-RESIDENT GRID of
// 2048 blocks (8/CU), __launch_bounds__(256,8). Each wave owns up to T=2
// tiles (stride = gridDim*4 = 8192). BAND OUTER, tile inner — all resident
// waves sweep the same src band simultaneously, so each XCD's L2 holds only
// that band's hbf slice (~2.8 MB < 4 MB) and re-touches hit.
// GATHER: the 4 grp-lanes of a node each load their OWN 16B quarter
// (ch 8*grp..+8) of every neighbor — no butterfly; accumulate straight into
// persistent keepT[t][8]. adj loads PLAIN (r8 lesson: NT hints on adj broke
// adjacent-segment cache-line sharing — FETCH +5MB, dur +8us).
// A-frag (16x16x32): lane holds A[row=col][k=grp*8+i]
// C/D: lane reg r = D[row=grp*4+r][col]   (m89)
// z2 stored as bf16. Prologue zeroes the *other* stats buffer.
__global__ __launch_bounds__(256, 8) void k_conv(
    const unsigned short* __restrict__ hbf,
    const int* __restrict__ adj, const int* __restrict__ rowseg,
    const int* __restrict__ degseg,
    const unsigned short* __restrict__ whb, const float* __restrict__ bh,
    const unsigned short* __restrict__ wob, const float* __restrict__ bo,
    const int* __restrict__ batch, unsigned short* __restrict__ z2,
    float* __restrict__ stats, float* __restrict__ statsOther, int N) {
  __shared__ unsigned short sWhB[4 * 64 * 8];     // [nt][lane][i]
  __shared__ unsigned short sWoB[2 * 2 * 64 * 8]; // [nt2*2+ks][lane][i]
  __shared__ unsigned short st[4][16][72];        // per-wave t buf, +8 pad

  {
    int zi = blockIdx.x * 256 + threadIdx.x;
    if (zi < NGRAPH * 64) statsOther[zi] = 0.f;
    int p = threadIdx.x * 8;
    *((ushort8v*)&sWhB[p]) = *((const ushort8v*)&whb[p]);
    *((ushort8v*)&sWoB[p]) = *((const ushort8v*)&wob[p]);
  }
  __syncthreads();

  int wid = threadIdx.x >> 6;
  int lane = threadIdx.x & 63;
  int col = lane & 15;
  int grp = lane >> 4;
  int gwave = blockIdx.x * 4 + wid;        // 0..8191
  int wstride = gridDim.x * 4;             // 8192
  int ntiles = (N + 15) >> 4;

  // quarter base: this lane only ever touches ch 8*grp..8*grp+7 of any row
  const unsigned short* __restrict__ qb = hbf + grp * 8;

  // persistent per-tile accumulators (lane grp holds ch 8*grp..8*grp+7)
  float keepT[2][8];
  #pragma unroll
  for (int t = 0; t < 2; t++)
    #pragma unroll
    for (int i = 0; i < 8; i++) keepT[t][i] = 0.f;

  // band-major gather sweep
  #pragma unroll
  for (int b = 0; b < 4; b++) {
    #pragma unroll
    for (int t = 0; t < 2; t++) {
      int tile = gwave + t * wstride;
      if (tile >= ntiles) continue;        // wave-uniform branch
      int node = tile * 16 + col;
      int s0 = 0, dg = 0;
      if (node < N) {
        s0 = rowseg[(size_t)node * 4 + b];
        dg = degseg[(size_t)node * 4 + b];
      }
      int k = 0;
      for (; k + 4 <= dg; k += 4) {
        int sA = adj[s0 + k + 0];
        int sB = adj[s0 + k + 1];
        int sC = adj[s0 + k + 2];
        int sD = adj[s0 + k + 3];
        ushort8v a = *((const ushort8v*)(qb + (size_t)sA * 32));
        ushort8v bv = *((const ushort8v*)(qb + (size_t)sB * 32));
        ushort8v c = *((const ushort8v*)(qb + (size_t)sC * 32));
        ushort8v d = *((const ushort8v*)(qb + (size_t)sD * 32));
        #pragma unroll
        for (int i = 0; i < 8; i++) {
          keepT[t][i] += bf2f(a[i]);
          keepT[t][i] += bf2f(bv[i]);
          keepT[t][i] += bf2f(c[i]);
          keepT[t][i] += bf2f(d[i]);
        }
      }
      if (k + 2 <= dg) {
        int sA = adj[s0 + k + 0];
        int sB = adj[s0 + k + 1];
        ushort8v a = *((const ushort8v*)(qb + (size_t)sA * 32));
        ushort8v bv = *((const ushort8v*)(qb + (size_t)sB * 32));
        #pragma unroll
        for (int i = 0; i < 8; i++) {
          keepT[t][i] += bf2f(a[i]);
          keepT[t][i] += bf2f(bv[i]);
        }
        k += 2;
      }
      if (k < dg) {
        int sA = adj[s0 + k];
        ushort8v a = *((const ushort8v*)(qb + (size_t)sA * 32));
        #pragma unroll
        for (int i = 0; i < 8; i++) keepT[t][i] += bf2f(a[i]);
      }
    }
  }

  // epilogue per tile: z -> MLP -> z2, stats
  #pragma unroll
  for (int t = 0; t < 2; t++) {
    int tile = gwave + t * wstride;
    if (tile >= ntiles) continue;
    int base = tile * 16;
    int node = base + col;

    float zf[8];
    if (node < N) {
      ushort8v own = *((const ushort8v*)(hbf + (size_t)node * 32 + grp * 8));
      #pragma unroll
      for (int i = 0; i < 8; i++) zf[i] = bf2f(own[i]) + keepT[t][i];
    } else {
      #pragma unroll
      for (int i = 0; i < 8; i++) zf[i] = 0.f;
    }
    short8v afrag;
    #pragma unroll
    for (int i = 0; i < 8; i++) afrag[i] = (short)f2bf(zf[i]);

    // layer 1: t1 = relu(z @ Wh + bh) -> bf16 in per-wave LDS
    #pragma unroll
    for (int nt = 0; nt < 4; nt++) {
      float b = bh[nt * 16 + col];
      float4v acc1 = {b, b, b, b};
      short8v bfrag = *((const short8v*)&sWhB[(nt * 64 + lane) * 8]);
      acc1 = __builtin_amdgcn_mfma_f32_16x16x32_bf16(afrag, bfrag, acc1, 0, 0, 0);
      #pragma unroll
      for (int r = 0; r < 4; r++) {
        st[wid][grp * 4 + r][nt * 16 + col] = f2bf(fmaxf(acc1[r], 0.f));
      }
    }
    // same-wave LDS RAW/WAR: DS ops are in-order per wave; compiler inserts lgkmcnt.

    // layer 2: o = t1 @ Wo + bo
    short8v a2[2];
    #pragma unroll
    for (int ks = 0; ks < 2; ks++)
      a2[ks] = *((const short8v*)&st[wid][col][ks * 32 + grp * 8]);

    float4v acc2[2];
    #pragma unroll
    for (int nt2 = 0; nt2 < 2; nt2++) {
      float b = bo[nt2 * 16 + col];
      acc2[nt2] = (float4v){b, b, b, b};
      #pragma unroll
      for (int ks = 0; ks < 2; ks++) {
        short8v bfrag = *((const short8v*)&sWoB[((nt2 * 2 + ks) * 64 + lane) * 8]);
        acc2[nt2] = __builtin_amdgcn_mfma_f32_16x16x32_bf16(a2[ks], bfrag, acc2[nt2], 0, 0, 0);
      }
    }

    // store z2 (bf16, nt streaming store)
    #pragma unroll
    for (int nt2 = 0; nt2 < 2; nt2++) {
      #pragma unroll
      for (int r = 0; r < 4; r++) {
        int nd = base + grp * 4 + r;
        if (nd < N)
          __builtin_nontemporal_store(f2bf(acc2[nt2][r]), z2 + (size_t)nd * 32 + nt2 * 16 + col);
      }
    }

    // per-graph stats
    int g0 = batch[base];
    int gLast = batch[min(base + 15, N - 1)];
    if ((base + 16 <= N) && g0 == gLast) {
      #pragma unroll
      for (int nt2 = 0; nt2 < 2; nt2++) {
        float s = acc2[nt2][0] + acc2[nt2][1] + acc2[nt2][2] + acc2[nt2][3];
        float ss = acc2[nt2][0] * acc2[nt2][0] + acc2[nt2][1] * acc2[nt2][1]
                 + acc2[nt2][2] * acc2[nt2][2] + acc2[nt2][3] * acc2[nt2][3];
        s += __shfl_xor(s, 16); s += __shfl_xor(s, 32);
        ss += __shfl_xor(ss, 16); ss += __shfl_xor(ss, 32);
        if (grp == 0) {
          atomicAdd(&stats[(size_t)g0 * 64 + nt2 * 16 + col], s);
          atomicAdd(&stats[(size_t)g0 * 64 + 32 + nt2 * 16 + col], ss);
        }
      }
    } else {
      #pragma unroll
      for (int nt2 = 0; nt2 < 2; nt2++) {
        #pragma unroll
        for (int r = 0; r < 4; r++) {
          int nd = base + grp * 4 + r;
          if (nd < N) {
            int g = batch[nd];
            float v = acc2[nt2][r];
            atomicAdd(&stats[(size_t)g * 64 + nt2 * 16 + col], v);
            atomicAdd(&stats[(size_t)g * 64 + 32 + nt2 * 16 + col], v * v);
          }
        }
      }
    }
  }
}

// ---------------- conv 0 specialization ----------------
// At conv 0, h = emb[x] has only 6 distinct rows, so the neighbor gather
// collapses to type-counting. Row is contiguous across band segments:
// start = seg0 start, deg = sum of seg degs.
__global__ __launch_bounds__(256, 4) void k_conv0(
    const unsigned short* __restrict__ hbf,
    const int* __restrict__ adj, const int* __restrict__ rowseg,
    const int* __restrict__ degseg,
    const int* __restrict__ x, const float* __restrict__ emb,
    const unsigned short* __restrict__ whb, const float* __restrict__ bh,
    const unsigned short* __restrict__ wob, const float* __restrict__ bo,
    const int* __restrict__ batch, unsigned short* __restrict__ z2,
    float* __restrict__ stats, float* __restrict__ statsOther, int N) {
  __shared__ unsigned short sWhB[4 * 64 * 8];
  __shared__ unsigned short sWoB[2 * 2 * 64 * 8];
  __shared__ unsigned short st[4][16][72];
  __shared__ float sEmb[6][32];

  {
    int zi = blockIdx.x * 256 + threadIdx.x;
    if (zi < NGRAPH * 64) statsOther[zi] = 0.f;
    int p = threadIdx.x * 8;
    *((ushort8v*)&sWhB[p]) = *((const ushort8v*)&whb[p]);
    *((ushort8v*)&sWoB[p]) = *((const ushort8v*)&wob[p]);
    if (threadIdx.x < 192) ((float*)sEmb)[threadIdx.x] = emb[threadIdx.x];
  }
  __syncthreads();

  int wid = threadIdx.x >> 6;
  int lane = threadIdx.x & 63;
  int tile = blockIdx.x * 4 + wid;
  int base = tile * 16;
  if (base >= N) return;
  int col = lane & 15;
  int grp = lane >> 4;
  int node = base + col;

  int s0 = 0, dg = 0;
  if (node < N) {
    int4 s4 = *((const int4*)(rowseg + (size_t)node * 4));
    int4 d4 = *((const int4*)(degseg + (size_t)node * 4));
    s0 = s4.x;
    dg = d4.x + d4.y + d4.z + d4.w;
  }

  // count neighbor types over this lane's subset (j == grp mod 4)
  float c0 = 0.f, c1 = 0.f, c2 = 0.f, c3 = 0.f, c4 = 0.f, c5 = 0.f;
  int j = grp;
  for (; j + 4 < dg; j += 8) {
    int sAi = __builtin_nontemporal_load(adj + s0 + j);
    int sBi = __builtin_nontemporal_load(adj + s0 + j + 4);
    int tA = x[sAi];
    int tB = x[sBi];
    c0 += (tA == 0) ? 1.f : 0.f; c1 += (tA == 1) ? 1.f : 0.f;
    c2 += (tA == 2) ? 1.f : 0.f; c3 += (tA == 3) ? 1.f : 0.f;
    c4 += (tA == 4) ? 1.f : 0.f; c5 += (tA == 5) ? 1.f : 0.f;
    c0 += (tB == 0) ? 1.f : 0.f; c1 += (tB == 1) ? 1.f : 0.f;
    c2 += (tB == 2) ? 1.f : 0.f; c3 += (tB == 3) ? 1.f : 0.f;
    c4 += (tB == 4) ? 1.f : 0.f; c5 += (tB == 5) ? 1.f : 0.f;
  }
  if (j < dg) {
    int sAi = __builtin_nontemporal_load(adj + s0 + j);
    int tA = x[sAi];
    c0 += (tA == 0) ? 1.f : 0.f; c1 += (tA == 1) ? 1.f : 0.f;
    c2 += (tA == 2) ? 1.f : 0.f; c3 += (tA == 3) ? 1.f : 0.f;
    c4 += (tA == 4) ? 1.f : 0.f; c5 += (tA == 5) ? 1.f : 0.f;
  }

  // all-reduce counts across the 4 grp-lanes of each node (col preserved)
  c0 += __shfl_xor(c0, 16); c0 += __shfl_xor(c0, 32);
  c1 += __shfl_xor(c1, 16); c1 += __shfl_xor(c1, 32);
  c2 += __shfl_xor(c2, 16); c2 += __shfl_xor(c2, 32);
  c3 += __shfl_xor(c3, 16); c3 += __shfl_xor(c3, 32);
  c4 += __shfl_xor(c4, 16); c4 += __shfl_xor(c4, 32);
  c5 += __shfl_xor(c5, 16); c5 += __shfl_xor(c5, 32);

  // z = h_own + sum_t c_t * emb[t]   (lane grp holds ch 8*grp..8*grp+7)
  float zf[8];
  if (node < N) {
    ushort8v own = *((const ushort8v*)(hbf + (size_t)node * 32 + grp * 8));
    #pragma unroll
    for (int i = 0; i < 8; i++) {
      int ch = grp * 8 + i;
      float v = bf2f(own[i]);
      v = fmaf(c0, sEmb[0][ch], v);
      v = fmaf(c1, sEmb[1][ch], v);
      v = fmaf(c2, sEmb[2][ch], v);
      v = fmaf(c3, sEmb[3][ch], v);
      v = fmaf(c4, sEmb[4][ch], v);
      v = fmaf(c5, sEmb[5][ch], v);
      zf[i] = v;
    }
  } else {
    #pragma unroll
    for (int i = 0; i < 8; i++) zf[i] = 0.f;
  }
  short8v afrag;
  #pragma unroll
  for (int i = 0; i < 8; i++) afrag[i] = (short)f2bf(zf[i]);

  // layer 1: t = relu(z @ Wh + bh) -> bf16 t in per-wave LDS
  #pragma unroll
  for (int nt = 0; nt < 4; nt++) {
    float b = bh[nt * 16 + col];
    float4v acc1 = {b, b, b, b};
    short8v bfrag = *((const short8v*)&sWhB[(nt * 64 + lane) * 8]);
    acc1 = __builtin_amdgcn_mfma_f32_16x16x32_bf16(afrag, bfrag, acc1, 0, 0, 0);
    #pragma unroll
    for (int r = 0; r < 4; r++) {
      st[wid][grp * 4 + r][nt * 16 + col] = f2bf(fmaxf(acc1[r], 0.f));
    }
  }

  // layer 2: o = t @ Wo + bo
  short8v a2[2];
  #pragma unroll
  for (int ks = 0; ks < 2; ks++)
    a2[ks] = *((const short8v*)&st[wid][col][ks * 32 + grp * 8]);

  float4v acc2[2];
  #pragma unroll
  for (int nt2 = 0; nt2 < 2; nt2++) {
    float b = bo[nt2 * 16 + col];
    acc2[nt2] = (float4v){b, b, b, b};
    #pragma unroll
    for (int ks = 0; ks < 2; ks++) {
      short8v bfrag = *((const short8v*)&sWoB[((nt2 * 2 + ks) * 64 + lane) * 8]);
      acc2[nt2] = __builtin_amdgcn_mfma_f32_16x16x32_bf16(a2[ks], bfrag, acc2[nt2], 0, 0, 0);
    }
  }

  // store z2 (bf16, nt streaming store)
  #pragma unroll
  for (int nt2 = 0; nt2 < 2; nt2++) {
    #pragma unroll
    for (int r = 0; r < 4; r++) {
      int nd = base + grp * 4 + r;
      if (nd < N)
        __builtin_nontemporal_store(f2bf(acc2[nt2][r]), z2 + (size_t)nd * 32 + nt2 * 16 + col);
    }
  }

  // per-graph stats
  int g0 = batch[base];
  int gLast = batch[min(base + 15, N - 1)];
  if ((base + 16 <= N) && g0 == gLast) {
    #pragma unroll
    for (int nt2 = 0; nt2 < 2; nt2++) {
      float s = acc2[nt2][0] + acc2[nt2][1] + acc2[nt2][2] + acc2[nt2][3];
      float ss = acc2[nt2][0] * acc2[nt2][0] + acc2[nt2][1] * acc2[nt2][1]
               + acc2[nt2][2] * acc2[nt2][2] + acc2[nt2][3] * acc2[nt2][3];
      s += __shfl_xor(s, 16); s += __shfl_xor(s, 32);
      ss += __shfl_xor(ss, 16); ss += __shfl_xor(ss, 32);
      if (grp == 0) {
        atomicAdd(&stats[(size_t)g0 * 64 + nt2 * 16 + col], s);
        atomicAdd(&stats[(size_t)g0 * 64 + 32 + nt2 * 16 + col], ss);
      }
    }
  } else {
    #pragma unroll
    for (int nt2 = 0; nt2 < 2; nt2++) {
      #pragma unroll
      for (int r = 0; r < 4; r++) {
        int nd = base + grp * 4 + r;
        if (nd < N) {
          int g = batch[nd];
          float v = acc2[nt2][r];
          atomicAdd(&stats[(size_t)g * 64 + nt2 * 16 + col], v);
          atomicAdd(&stats[(size_t)g * 64 + 32 + nt2 * 16 + col], v * v);
        }
      }
    }
  }
}

// h = relu(h + (z2-mean)*inv) with h kept in bf16 (hbf); mean/inv computed
// per-thread from stats+counts (tiny L2-resident tables). 8 threads/node.
// (r5 verbatim — the 4-thr/node variant regressed in r8.)
__global__ __launch_bounds__(256) void k_norm(
    unsigned short* __restrict__ hbf, const unsigned short* __restrict__ z2,
    const float* __restrict__ stats, const float* __restrict__ counts,
    const int* __restrict__ batch, float* __restrict__ pooled, int conv, int N) {
  long t = (long)blockIdx.x * blockDim.x + threadIdx.x;
  int n = (int)(t >> 3), q = (int)(t & 7);
  int lane = threadIdx.x & 63;
  bool valid = (n < N);

  int g = 0;
  float r0 = -INFINITY, r1 = -INFINITY, r2 = -INFINITY, r3 = -INFINITY;
  if (valid) {
    g = batch[n];
    float cnt = counts[g];
    float4 sv = *((const float4*)(stats + (size_t)g * 64 + q * 4));
    float4 qv = *((const float4*)(stats + (size_t)g * 64 + 32 + q * 4));
    float m0 = 0.f, m1 = 0.f, m2 = 0.f, m3 = 0.f;
    float i0 = 0.f, i1 = 0.f, i2 = 0.f, i3 = 0.f;
    if (cnt > 0.f) {
      m0 = sv.x / cnt; m1 = sv.y / cnt; m2 = sv.z / cnt; m3 = sv.w / cnt;
      i0 = rsqrtf(fmaxf(qv.x / cnt - m0 * m0, 0.f) + EPS);
      i1 = rsqrtf(fmaxf(qv.y / cnt - m1 * m1, 0.f) + EPS);
      i2 = rsqrtf(fmaxf(qv.z / cnt - m2 * m2, 0.f) + EPS);
      i3 = rsqrtf(fmaxf(qv.w / cnt - m3 * m3, 0.f) + EPS);
    }
    ushort4v hb = *((const ushort4v*)(hbf + (size_t)n * 32 + q * 4));
    ushort4v zv = *((const ushort4v*)(z2 + (size_t)n * 32 + q * 4));
    r0 = fmaxf(bf2f(hb[0]) + (bf2f(zv[0]) - m0) * i0, 0.f);
    r1 = fmaxf(bf2f(hb[1]) + (bf2f(zv[1]) - m1) * i1, 0.f);
    r2 = fmaxf(bf2f(hb[2]) + (bf2f(zv[2]) - m2) * i2, 0.f);
    r3 = fmaxf(bf2f(hb[3]) + (bf2f(zv[3]) - m3) * i3, 0.f);
    hb[0] = f2bf(r0); hb[1] = f2bf(r1); hb[2] = f2bf(r2); hb[3] = f2bf(r3);
    *((ushort4v*)(hbf + (size_t)n * 32 + q * 4)) = hb;
  }

  // pool: max over the wave's 8 nodes per channel
  int g0 = __shfl(g, 0);
  bool uniform = __all(valid) && __all(g == g0);
  if (uniform) {
    float m0 = r0, m1 = r1, m2 = r2, m3 = r3;
    #pragma unroll
    for (int d = 8; d < 64; d <<= 1) {
      m0 = fmaxf(m0, __shfl_xor(m0, d));
      m1 = fmaxf(m1, __shfl_xor(m1, d));
      m2 = fmaxf(m2, __shfl_xor(m2, d));
      m3 = fmaxf(m3, __shfl_xor(m3, d));
    }
    if (lane < 8) {
      float* poolrow = pooled + (size_t)g0 * FEATS + (conv + 1) * 32 + lane * 4;
      atomicMaxF(poolrow + 0, m0);
      atomicMaxF(poolrow + 1, m1);
      atomicMaxF(poolrow + 2, m2);
      atomicMaxF(poolrow + 3, m3);
    }
  } else if (valid) {
    float* poolrow = pooled + (size_t)g * FEATS + (conv + 1) * 32 + q * 4;
    atomicMaxF(poolrow + 0, r0);
    atomicMaxF(poolrow + 1, r1);
    atomicMaxF(poolrow + 2, r2);
    atomicMaxF(poolrow + 3, r3);
  }
}

// hid = relu(pooled @ W_hid + b_hid); out = hid @ W_out + b_out
__global__ __launch_bounds__(64) void k_head(
    const float* __restrict__ pooled, const float* __restrict__ W_hid,
    const float* __restrict__ b_hid, const float* __restrict__ W_out,
    const float* __restrict__ b_out, float* __restrict__ out) {
  __shared__ float sp[FEATS];
  __shared__ float sh[64];
  int g = blockIdx.x;
  for (int i = threadIdx.x; i < FEATS; i += 64) sp[i] = pooled[(size_t)g * FEATS + i];
  __syncthreads();
  int j = threadIdx.x;
  float acc = b_hid[j];
  for (int k = 0; k < FEATS; k++) acc = fmaf(sp[k], W_hid[k * 64 + j], acc);
  sh[j] = fmaxf(acc, 0.f);
  __syncthreads();
  if (j < 32) {
    float o = b_out[j];
    #pragma unroll
    for (int k = 0; k < 64; k++) o = fmaf(sh[k], W_out[k * 32 + j], o);
    out[(size_t)g * 32 + j] = o;
  }
}

extern "C" void kernel_launch(void* const* d_in, const int* in_sizes, int n_in,
                              void* d_out, int out_size, void* d_ws, size_t ws_size,
                              hipStream_t stream) {
  const int* x      = (const int*)d_in[0];
  const int* edge   = (const int*)d_in[1];
  const int* batch  = (const int*)d_in[2];
  const float* emb  = (const float*)d_in[3];
  const float* Wh   = (const float*)d_in[4];
  const float* bh   = (const float*)d_in[5];
  const float* Wo   = (const float*)d_in[6];
  const float* bo   = (const float*)d_in[7];
  const float* W_hid = (const float*)d_in[8];
  const float* b_hid = (const float*)d_in[9];
  const float* W_out = (const float*)d_in[10];
  const float* b_out = (const float*)d_in[11];
  float* out = (float*)d_out;

  int N = in_sizes[0];
  int E = in_sizes[1] / 2;
  const int* src = edge;
  const int* dst = edge + E;

  int N4 = N * 4;
  int bandsz = (N + NBAND - 1) / NBAND;   // src band size (hbf slice 3.2 MB)

  float* ws = (float*)d_ws;
  size_t off = 0;
  unsigned short* z2 = (unsigned short*)(ws + off); off += (size_t)N * 16; // N*32 bf16
  float* pooled  = ws + off; off += (size_t)NGRAPH * FEATS;
  float* stats   = ws + off; off += (size_t)NGRAPH * 128;   // double buffer
  float* counts  = ws + off; off += NGRAPH;
  unsigned short* hbf = (unsigned short*)(ws + off); off += (size_t)N * 16; // N*32 ushorts
  unsigned short* whb = (unsigned short*)(ws + off); off += 8192;  // 8*2048 ushorts
  unsigned short* wob = (unsigned short*)(ws + off); off += 8192;
  int* iws = (int*)(ws + off);
  size_t ioff = 0;
  int* degseg   = iws + ioff; ioff += N4;   // [dst][srcband]
  int* rowseg   = iws + ioff; ioff += N4;
  int* cursor   = iws + ioff; ioff += N4;
  int* adj      = iws + ioff; ioff += E;
  int* bsum     = iws + ioff; ioff += 4096;
  int* typemask = iws + ioff; ioff += NGRAPH;

  int eb = (E + 255) / 256;
  int nb4 = (N4 + 255) / 256;               // scan over 4N segment counters
  int nb8 = (int)(((size_t)N * 8 + 255) / 256);
  int tiles = (N + 15) / 16;
  int mb = (tiles + 3) / 4;   // conv0: 4 waves (tiles) per block
  int ib = nb4;               // k_init grid covers max(4N, NGRAPH*FEATS)
  if (ib < (NGRAPH * FEATS + 255) / 256) ib = (NGRAPH * FEATS + 255) / 256;

  int dband = (N + NBAND - 1) / NBAND;

  k_init<<<ib, 256, 0, stream>>>(pooled, counts, stats, degseg, typemask,
                                 Wh, Wo, whb, wob, N4);
  k_embed<<<nb8, 256, 0, stream>>>(x, batch, emb, hbf, typemask, counts, N);
  k_pool0<<<(NGRAPH * 32 + 255) / 256, 256, 0, stream>>>(typemask, emb, pooled);

  // CSR build: banded hist + banded scatter, each ONE launch
  // (band = blockIdx/eb; blocks dispatch in ID order -> temporal banding kept)
  k_hist<<<NBAND * eb, 256, 0, stream>>>(dst, src, degseg, E, eb, dband, bandsz, N);
  k_scan_block<<<nb4, 256, 0, stream>>>(degseg, rowseg, bsum, N4);
  k_scan_bsum<<<1, 256, 0, stream>>>(bsum, nb4);
  k_scan_add<<<nb4, 256, 0, stream>>>(rowseg, bsum, cursor, N4);
  k_scatter<<<NBAND * eb, 256, 0, stream>>>(src, dst, cursor, adj, E, eb, dband, bandsz, N);

  // fully co-resident conv grid: 8 blocks/CU x 256 CUs
  const int GCONV = 2048;

  for (int i = 0; i < 8; i++) {
    float* sCur = stats + (size_t)(i & 1) * NGRAPH * 64;
    float* sOth = stats + (size_t)((i + 1) & 1) * NGRAPH * 64;
    if (i == 0) {
      k_conv0<<<mb, 256, 0, stream>>>(hbf, adj, rowseg, degseg, x, emb,
                                      whb, bh, wob, bo,
                                      batch, z2, sCur, sOth, N);
    } else {
      k_conv<<<GCONV, 256, 0, stream>>>(hbf, adj, rowseg, degseg,
                                        whb + (size_t)i * 2048, bh + (size_t)i * 64,
                                        wob + (size_t)i * 2048, bo + (size_t)i * 32,
                                        batch, z2, sCur, sOth, N);
    }
    k_norm<<<nb8, 256, 0, stream>>>(hbf, z2, sCur, counts, batch, pooled, i, N);
  }
  k_head<<<NGRAPH, 64, 0, stream>>>(pooled, W_hid, b_hid, W_out, b_out, out);
}